// Round 1
// baseline (592.214 us; speedup 1.0000x reference)
//
#include <hip/hip_runtime.h>

#define ENT 200
#define RELD 200
#define NBATCH 16384
#define MARGIN 4.0f

__device__ __forceinline__ float wave_reduce(float v) {
#pragma unroll
    for (int off = 32; off > 0; off >>= 1) v += __shfl_down(v, off, 64);
    return v;
}

// One block (256 threads) per batch element.
// Thread j (< 200) owns output rel-dimension j of all four projections.
__global__ __launch_bounds__(256) void transr_elem_kernel(
    const int* __restrict__ pos_h, const int* __restrict__ pos_t,
    const int* __restrict__ pos_r, const int* __restrict__ neg_h,
    const int* __restrict__ neg_t, const float* __restrict__ ent_emb,
    const float* __restrict__ rel_emb, const float* __restrict__ transfer,
    float* __restrict__ elem_loss)
{
    __shared__ float sv[ENT][4];   // interleaved {h, t, nh, nt}[e] -> one b128 broadcast per e
    __shared__ float sr[RELD];
    __shared__ float sred[4 * 8];  // per-wave partials (4 waves x up to 8 values)
    __shared__ float sres[8];      // broadcast rsqrt results

    const int b   = blockIdx.x;
    const int tid = threadIdx.x;

    const int ph = pos_h[b];
    const int pt = pos_t[b];
    const int pr = pos_r[b];
    const int nh = neg_h[b];
    const int nt = neg_t[b];

    if (tid < ENT) {
        sv[tid][0] = ent_emb[(size_t)ph * ENT + tid];
        sv[tid][1] = ent_emb[(size_t)pt * ENT + tid];
        sv[tid][2] = ent_emb[(size_t)nh * ENT + tid];
        sv[tid][3] = ent_emb[(size_t)nt * ENT + tid];
        sr[tid]    = rel_emb[(size_t)pr * RELD + tid];
    }
    __syncthreads();

    float a0 = 0.f, a1 = 0.f, a2 = 0.f, a3 = 0.f;
    if (tid < RELD) {
        // column j of M = transfer[pr] (row-major [ENT][RELD]); coalesced across lanes
        const float* __restrict__ Mj = transfer + (size_t)pr * (ENT * RELD) + tid;
#pragma unroll 8
        for (int e = 0; e < ENT; ++e) {
            const float4 v = *(const float4*)(&sv[e][0]);  // LDS broadcast (same addr all lanes)
            const float  m = Mj[(size_t)e * RELD];
            a0 = fmaf(v.x, m, a0);
            a1 = fmaf(v.y, m, a1);
            a2 = fmaf(v.z, m, a2);
            a3 = fmaf(v.w, m, a3);
        }
    }
    const float srj = (tid < RELD) ? sr[tid] : 0.f;

    const int lane = tid & 63;
    const int wv   = tid >> 6;

    // 5 squared-norm reductions: p_h, p_t, n_h, n_t projections + rel vector
    float vals[5] = {a0 * a0, a1 * a1, a2 * a2, a3 * a3, srj * srj};
#pragma unroll
    for (int k = 0; k < 5; ++k) {
        const float s = wave_reduce(vals[k]);
        if (lane == 0) sred[wv * 8 + k] = s;
    }
    __syncthreads();
    if (tid < 5) {
        const float ss = sred[0 * 8 + tid] + sred[1 * 8 + tid] +
                         sred[2 * 8 + tid] + sred[3 * 8 + tid];
        sres[tid] = rsqrtf(fmaxf(ss, 1e-12f));
    }
    __syncthreads();

    const float r0 = sres[0], r1 = sres[1], r2 = sres[2], r3 = sres[3], rr = sres[4];
    const float pj = fabsf(a0 * r0 + srj * rr - a1 * r1);
    const float nj = fabsf(a2 * r2 + srj * rr - a3 * r3);

    const float ps = wave_reduce(pj);
    const float ns = wave_reduce(nj);
    if (lane == 0) { sred[wv * 8 + 0] = ps; sred[wv * 8 + 1] = ns; }
    __syncthreads();
    if (tid == 0) {
        const float P = sred[0] + sred[8] + sred[16] + sred[24];
        const float N = sred[1] + sred[9] + sred[17] + sred[25];
        elem_loss[b] = fmaxf(P - N + MARGIN, 0.f);
    }
}

// Deterministic final mean: single block, 256 threads.
__global__ __launch_bounds__(256) void reduce_mean_kernel(
    const float* __restrict__ elem, float* __restrict__ out)
{
    __shared__ float sred[4];
    float s = 0.f;
    for (int i = threadIdx.x; i < NBATCH; i += 256) s += elem[i];
    s = wave_reduce(s);
    const int lane = threadIdx.x & 63;
    const int wv   = threadIdx.x >> 6;
    if (lane == 0) sred[wv] = s;
    __syncthreads();
    if (threadIdx.x == 0)
        out[0] = (sred[0] + sred[1] + sred[2] + sred[3]) * (1.0f / (float)NBATCH);
}

extern "C" void kernel_launch(void* const* d_in, const int* in_sizes, int n_in,
                              void* d_out, int out_size, void* d_ws, size_t ws_size,
                              hipStream_t stream) {
    const int*   pos_h    = (const int*)d_in[0];
    const int*   pos_t    = (const int*)d_in[1];
    const int*   pos_r    = (const int*)d_in[2];
    const int*   neg_h    = (const int*)d_in[3];
    const int*   neg_t    = (const int*)d_in[4];
    const float* ent_emb  = (const float*)d_in[5];
    const float* rel_emb  = (const float*)d_in[6];
    const float* transfer = (const float*)d_in[7];

    float* elem_loss = (float*)d_ws;   // 16384 floats of scratch
    float* out       = (float*)d_out;

    transr_elem_kernel<<<NBATCH, 256, 0, stream>>>(
        pos_h, pos_t, pos_r, neg_h, neg_t, ent_emb, rel_emb, transfer, elem_loss);
    reduce_mean_kernel<<<1, 256, 0, stream>>>(elem_loss, out);
}